// Round 2
// baseline (616.263 us; speedup 1.0000x reference)
//
#include <hip/hip_runtime.h>
#include <stdint.h>

#define B_ 2
#define M_ 4096
#define N_ 4096
#define K_ 4096
#define KW 64   // u64 words per K-row
#define KP 32   // uint4 (u64-pair) units per K-row
#define NCH 8   // K chunks
#define CP 4    // uint4 pairs per chunk (8 kw)
#define TM 128
#define TN 128

// Pack sign bits: each wave packs a 256-float group -> 4 u64 words via ballot.
// Bit order is a fixed K-permutation, identical for x and y => dots unchanged.
// Invariant: ngroups % (2*nwaves) == 0 (grid chosen to make iters exact).
__global__ __launch_bounds__(256) void pack_signs2(
    const float* __restrict__ x, const float* __restrict__ y,
    unsigned long long* __restrict__ px, unsigned long long* __restrict__ py,
    int ngroups) {
    const float* in = blockIdx.y ? y : x;
    unsigned long long* out = blockIdx.y ? py : px;
    int lane   = threadIdx.x & 63;
    int wave   = (blockIdx.x * blockDim.x + threadIdx.x) >> 6;
    int nwaves = (gridDim.x * blockDim.x) >> 6;
    for (int g = wave; g < ngroups; g += 2 * nwaves) {
        int g1 = g + nwaves;
        float4 v0 = *(const float4*)(in + (size_t)g * 256 + lane * 4);
        float4 v1 = *(const float4*)(in + (size_t)g1 * 256 + lane * 4);
        unsigned long long a0 = __ballot(v0.x >= 0.0f);
        unsigned long long a1 = __ballot(v0.y >= 0.0f);
        unsigned long long a2 = __ballot(v0.z >= 0.0f);
        unsigned long long a3 = __ballot(v0.w >= 0.0f);
        unsigned long long b0 = __ballot(v1.x >= 0.0f);
        unsigned long long b1 = __ballot(v1.y >= 0.0f);
        unsigned long long b2 = __ballot(v1.z >= 0.0f);
        unsigned long long b3 = __ballot(v1.w >= 0.0f);
        if (lane == 0) {
            ulonglong2* o0 = (ulonglong2*)(out + (size_t)g * 4);
            o0[0] = make_ulonglong2(a0, a1);
            o0[1] = make_ulonglong2(a2, a3);
            ulonglong2* o1 = (ulonglong2*)(out + (size_t)g1 * 4);
            o1[0] = make_ulonglong2(b0, b1);
            o1[1] = make_ulonglong2(b2, b3);
        }
    }
}

// Binary GEMM: C = (K - 2*popcount(a XOR b)) * scale.
// 128x128 tile, 256 threads, 8x8 per thread (rows ty+16i, cols tx+16j).
// LDS layout: [buf][pair][row ^ 2*pair] of uint4 (2 kw words) — XOR swizzle
// makes staging writes / B-reads 2-way (free) and A-reads broadcasts.
// Ping-pong LDS + register prefetch: one barrier per K-chunk.
__global__ __launch_bounds__(256) void bgemm(
    const uint4* __restrict__ pa, const uint4* __restrict__ pb,
    float* __restrict__ out, const float* __restrict__ xclip,
    const float* __restrict__ yclip) {
    __shared__ uint4 As[2][CP][TM];
    __shared__ uint4 Bs[2][CP][TM];

    const int b  = blockIdx.z;
    const int m0 = blockIdx.x * TM;
    const int n0 = blockIdx.y * TN;
    const int t  = threadIdx.x;
    const int tx = t & 15;
    const int ty = t >> 4;

    const uint4* ga = pa + ((size_t)b * M_ + m0) * KP;
    const uint4* gb = pb + ((size_t)b * N_ + n0) * KP;

    // staging map: unit0 = (row r0, pair cp0), unit1 = (row r0+64, pair cp0)
    const int r0  = t >> 2;
    const int cp0 = t & 3;
    const int sw0 = r0 ^ (2 * cp0);
    const int sw1 = (r0 + 64) ^ (2 * cp0);

    unsigned acc[8][8] = {};

    // preload + stage chunk 0
    uint4 va0 = ga[(size_t)r0 * KP + cp0];
    uint4 va1 = ga[(size_t)(r0 + 64) * KP + cp0];
    uint4 vb0 = gb[(size_t)r0 * KP + cp0];
    uint4 vb1 = gb[(size_t)(r0 + 64) * KP + cp0];
    As[0][cp0][sw0] = va0;
    As[0][cp0][sw1] = va1;
    Bs[0][cp0][sw0] = vb0;
    Bs[0][cp0][sw1] = vb1;
    __syncthreads();

    for (int c = 0; c < NCH; ++c) {
        const int buf = c & 1;
        if (c + 1 < NCH) {  // prefetch next chunk into regs (hidden by compute)
            const int ko = (c + 1) * CP;
            va0 = ga[(size_t)r0 * KP + ko + cp0];
            va1 = ga[(size_t)(r0 + 64) * KP + ko + cp0];
            vb0 = gb[(size_t)r0 * KP + ko + cp0];
            vb1 = gb[(size_t)(r0 + 64) * KP + ko + cp0];
        }
#pragma unroll
        for (int p = 0; p < CP; ++p) {
            uint4 bv[8];
#pragma unroll
            for (int j = 0; j < 8; ++j) bv[j] = Bs[buf][p][(tx + 16 * j) ^ (2 * p)];
#pragma unroll
            for (int i = 0; i < 8; ++i) {
                uint4 av = As[buf][p][(ty + 16 * i) ^ (2 * p)];
#pragma unroll
                for (int j = 0; j < 8; ++j) {
                    // add(ctpop) fuses into v_bcnt_u32_b32 accumulate: 8 ops/128 MACs
                    acc[i][j] += __popc(av.x ^ bv[j].x);
                    acc[i][j] += __popc(av.y ^ bv[j].y);
                    acc[i][j] += __popc(av.z ^ bv[j].z);
                    acc[i][j] += __popc(av.w ^ bv[j].w);
                }
            }
        }
        if (c + 1 < NCH) {  // write prefetched regs into the other buffer
            const int nbuf = buf ^ 1;
            As[nbuf][cp0][sw0] = va0;
            As[nbuf][cp0][sw1] = va1;
            Bs[nbuf][cp0][sw0] = vb0;
            Bs[nbuf][cp0][sw1] = vb1;
        }
        __syncthreads();
    }

    const float scale = xclip[0] * yclip[0];
#pragma unroll
    for (int i = 0; i < 8; ++i) {
        int m = m0 + ty + 16 * i;
        float* orow = out + ((size_t)b * M_ + m) * (size_t)N_ + n0;
#pragma unroll
        for (int j = 0; j < 8; ++j) {
            int n = tx + 16 * j;
            orow[n] = scale * (float)(K_ - 2 * (int)acc[i][j]);
        }
    }
}

extern "C" void kernel_launch(void* const* d_in, const int* in_sizes, int n_in,
                              void* d_out, int out_size, void* d_ws, size_t ws_size,
                              hipStream_t stream) {
    const float* x     = (const float*)d_in[0];
    const float* y     = (const float*)d_in[1];
    const float* xclip = (const float*)d_in[2];
    const float* yclip = (const float*)d_in[3];
    float* out = (float*)d_out;

    unsigned long long* pa = (unsigned long long*)d_ws;   // [B][M][KW] = 4 MB
    unsigned long long* pb = pa + (size_t)B_ * M_ * KW;   // [B][N][KW] = 4 MB

    const int ngroups = B_ * M_ * K_ / 256;  // 131072 per input
    hipLaunchKernelGGL(pack_signs2, dim3(2048, 2), dim3(256), 0, stream,
                       x, y, pa, pb, ngroups);

    dim3 grid(M_ / TM, N_ / TN, B_);
    hipLaunchKernelGGL(bgemm, grid, dim3(256), 0, stream,
                       (const uint4*)pa, (const uint4*)pb, out, xclip, yclip);
}